// Round 6
// baseline (128.522 us; speedup 1.0000x reference)
//
#include <hip/hip_runtime.h>
#include <math.h>

#define DD 16
#define KK 1024
#define RPB 64          // rows per block; each of 4 waves covers one K-slice
#define NT 256
#define SLICES 4
#define JSL (KK / SLICES)

__device__ __forceinline__ float xformF(float v, float mn, float mx) {
  return (v / (1.f + fabsf(v)) + 1.f) * 0.5f * (mx - mn) + mn;
}
// f64 anchor transform, literal: t=a/(1+|a|); (t+1)*0.5*scale + box_min
__device__ __forceinline__ double xformD(double rv, double mn, double scl) {
  double t = rv / (1.0 + fabs(rv));
  return (t + 1.0) * 0.5 * scl + mn;
}

__global__ __launch_bounds__(NT, 2) void vor_main(
    const float* __restrict__ x_in, const float* __restrict__ logp_in,
    const float* __restrict__ an1_w, const float* __restrict__ an1_b,
    const float* __restrict__ an2_w, const float* __restrict__ an2_b,
    const float* __restrict__ shift_c, const float* __restrict__ anchor_raw,
    const float* __restrict__ box_min, const float* __restrict__ box_max,
    const float* __restrict__ mlogits,
    float* __restrict__ out, int Brows)
{
  __shared__ __align__(16) float sA[KK][DD];   // f32 anchors (selection only)
  __shared__ float  sAsqH[KK];                 // 0.5*||a_j||^2 (f32, selection only)
  __shared__ float  sX4T[DD][RPB];
  __shared__ int    sPj1[SLICES][RPB], sPj2[SLICES][RPB];
  __shared__ int    sRI1[SLICES][RPB], sRI2[SLICES][RPB];
  __shared__ double sPartD[8];
  __shared__ double sE1D[DD], sB1D[DD], sOmcD[DD], sB2D[DD], sE2D[DD];
  __shared__ double sMnD[DD], sMxD[DD], sSclD[DD], sDimD[DD];
  __shared__ double sBaseD;
  __shared__ int    sKidx[RPB];

  const int tid  = threadIdx.x;
  const int sl   = tid >> 6;
  const int lane = tid & 63;
  const int row  = blockIdx.x * RPB + lane;
  const size_t coreEnd = (size_t)Brows * (DD + 1);   // x then logp, f32 elements

  // ---- stage f32 anchors + f64 per-dim constants ----
  for (int e = tid; e < KK * DD / 4; e += NT) {
    float4 raw = ((const float4*)anchor_raw)[e];
    float4 bmn = ((const float4*)box_min)[e & 3];
    float4 bmx = ((const float4*)box_max)[e & 3];
    float4 o;
    o.x = xformF(raw.x, bmn.x, bmx.x);
    o.y = xformF(raw.y, bmn.y, bmx.y);
    o.z = xformF(raw.z, bmn.z, bmx.z);
    o.w = xformF(raw.w, bmn.w, bmx.w);
    ((float4*)sA)[e] = o;
  }
  if (tid < DD) {
    double w1 = (double)an1_w[tid];
    sE1D[tid] = exp(w1);
    sB1D[tid] = (double)an1_b[tid];
    double sgc = 1.0 / (1.0 + exp(-(double)shift_c[tid]));
    double c = sgc * 0.98 + 0.01;
    sOmcD[tid] = 1.0 - c;
    double mn = (double)box_min[tid], mx = (double)box_max[tid];
    sMnD[tid] = mn; sMxD[tid] = mx; sSclD[tid] = mx - mn;
    double w2 = (double)an2_w[tid];
    sE2D[tid] = exp(w2);
    sB2D[tid] = (double)an2_b[tid];
    sDimD[tid] = -w1 - log(mx - mn) - log1p(-c) - w2;
  }
  __syncthreads();

  for (int j = tid; j < KK; j += NT) {
    float acc = 0.f;
    #pragma unroll
    for (int d = 0; d < DD; ++d) { float a = sA[j][d]; acc = fmaf(a, a, acc); }
    sAsqH[j] = 0.5f * acc;
  }

  // ---- logsumexp(mixture_logits): wave-reduce, f64 sum ----
  float lm = -3.4e38f;
  for (int i = tid; i < KK; i += NT) lm = fmaxf(lm, mlogits[i]);
  #pragma unroll
  for (int o = 32; o > 0; o >>= 1) lm = fmaxf(lm, __shfl_xor(lm, o));
  if (lane == 0) sPartD[sl] = (double)lm;
  __syncthreads();
  float gmax = (float)fmax(fmax(sPartD[0], sPartD[1]), fmax(sPartD[2], sPartD[3]));
  double lsum = 0.0;
  for (int i = tid; i < KK; i += NT) lsum += exp((double)mlogits[i] - (double)gmax);
  #pragma unroll
  for (int o = 32; o > 0; o >>= 1) lsum += __shfl_xor(lsum, o);
  if (lane == 0) sPartD[4 + sl] = lsum;
  __syncthreads();
  if (tid == 0) {
    double lse = (double)gmax + log(sPartD[4] + sPartD[5] + sPartD[6] + sPartD[7]);
    double b = (double)DD * (log(0.98) + log(1.0 + 2.0 * (0.01 / 0.98)));
    #pragma unroll
    for (int d = 0; d < DD; ++d) b += sDimD[d];
    sBaseD = b + lse;
  }

  // ---- per-row f64 transform (wave 0), literal chain ----
  double x4d[DD];
  double lsigD = 0.0;
  if (sl == 0) {
    const double A = 0.01, EPSB = 0.01 / 0.98;
    const double SPAN = 1.0 + 2.0 * EPSB;
    const float* xr = x_in + (size_t)row * DD;
    #pragma unroll
    for (int d = 0; d < DD; ++d) {
      double y1 = ((double)xr[d] + sB1D[d]) * sE1D[d];
      double sg = 1.0 / (1.0 + exp(-y1));
      double x2 = (sg - A) / (1.0 - 2.0 * A);
      double x3 = (x2 + EPSB) / SPAN;
      double x4 = x3 * sSclD[d] + sMnD[d];
      x4d[d] = x4;
      sX4T[d][lane] = (float)x4;
      double ay = fabs(y1);
      lsigD += ay + 2.0 * log1p(exp(-ay));   // -(logsig(y)+logsig(-y))
    }
  }
  // ---- zero this block's f32 mask stripe (rows [blk*64, +64) x KK) ----
  {
    float4* mz = (float4*)(out + coreEnd + (size_t)blockIdx.x * RPB * KK);
    #pragma unroll 4
    for (int i = tid; i < RPB * KK / 4; i += NT)
      mz[i] = make_float4(0.f, 0.f, 0.f, 0.f);
  }
  __syncthreads();

  float x4f[DD];
  #pragma unroll
  for (int d = 0; d < DD; ++d) x4f[d] = sX4T[d][lane];

  // ---- sweep 1 (f32): top-2 of m = x·a - 0.5||a||^2 per slice ----
  float m1 = -3.4e38f, m2v = -3.4e38f;
  int j1 = 0x7fffffff, j2v = 0x7fffffff;
  const int jlo = sl * JSL, jhi = jlo + JSL;
  #pragma unroll 2
  for (int j = jlo; j < jhi; ++j) {
    float acc = -sAsqH[j];
    const float4* ar = (const float4*)&sA[j][0];
    #pragma unroll
    for (int dq = 0; dq < 4; ++dq) {
      float4 a4 = ar[dq];
      acc = fmaf(x4f[4 * dq + 0], a4.x, acc);
      acc = fmaf(x4f[4 * dq + 1], a4.y, acc);
      acc = fmaf(x4f[4 * dq + 2], a4.z, acc);
      acc = fmaf(x4f[4 * dq + 3], a4.w, acc);
    }
    bool gt1 = acc > m1;
    bool gt2 = acc > m2v;
    m2v = gt1 ? m1 : (gt2 ? acc : m2v);
    j2v = gt1 ? j1 : (gt2 ? j : j2v);
    m1  = gt1 ? acc : m1;
    j1  = gt1 ? j : j1;
  }
  sPj1[sl][lane] = j1;
  sPj2[sl][lane] = j2v;
  __syncthreads();

  // ---- wave 0: f64 re-evaluation of the 8 argmin candidates ----
  if (sl == 0) {
    double best = 1e300; int bk = 0x7fffffff;
    #pragma unroll
    for (int ss = 0; ss < SLICES; ++ss) {
      #pragma unroll
      for (int t = 0; t < 2; ++t) {
        int j = t ? sPj2[ss][lane] : sPj1[ss][lane];
        double asq = 0.0, dot = 0.0;
        #pragma unroll
        for (int d = 0; d < DD; ++d) {
          double a = xformD((double)anchor_raw[j * DD + d], sMnD[d], sSclD[d]);
          asq = fma(a, a, asq);
          dot = fma(x4d[d], a, dot);
        }
        double d2 = asq - 2.0 * dot;
        if (d2 < best || (d2 == best && j < bk)) { best = d2; bk = j; }
      }
    }
    sKidx[lane] = bk;
  }
  __syncthreads();

  const int k = sKidx[lane];

  // ---- sweep 2 (f32): top-2 ratio candidates (max q/h) per slice ----
  float akf[DD], dxf[DD];
  float r2f = 0.f, dxak = 0.f;
  #pragma unroll
  for (int d = 0; d < DD; ++d) {
    float a = sA[k][d];
    akf[d] = a;
    float dx = (float)sOmcD[d] * (x4f[d] - a);
    dxf[d] = dx;
    r2f  = fmaf(dx, dx, r2f);
    dxak = fmaf(dx, a, dxak);
  }
  const float epsr = 1e-12f * fmaxf(sqrtf(r2f), 1e-12f);
  const float asqhk = sAsqH[k];

  float q1 = 0.f, h1 = 1.f, q2 = 0.f, h2 = 1.f;
  int i1 = -1, i2 = -1;
  #pragma unroll 2
  for (int j = jlo; j < jhi; ++j) {
    float q = -dxak;
    float h = asqhk + sAsqH[j];
    const float4* ar = (const float4*)&sA[j][0];
    #pragma unroll
    for (int dq = 0; dq < 4; ++dq) {
      float4 a4 = ar[dq];
      q = fmaf(dxf[4 * dq + 0], a4.x, q);
      q = fmaf(dxf[4 * dq + 1], a4.y, q);
      q = fmaf(dxf[4 * dq + 2], a4.z, q);
      q = fmaf(dxf[4 * dq + 3], a4.w, q);
      h = fmaf(-akf[4 * dq + 0], a4.x, h);
      h = fmaf(-akf[4 * dq + 1], a4.y, h);
      h = fmaf(-akf[4 * dq + 2], a4.z, h);
      h = fmaf(-akf[4 * dq + 3], a4.w, h);
    }
    bool valid = (j != k) & (q > epsr);
    bool b1 = valid && (q * h1 > q1 * h);
    bool b2 = valid && (q * h2 > q2 * h);
    float nq2 = b1 ? q1 : (b2 ? q : q2);
    float nh2 = b1 ? h1 : (b2 ? h : h2);
    int   ni2 = b1 ? i1 : (b2 ? j : i2);
    q1 = b1 ? q : q1; h1 = b1 ? h : h1; i1 = b1 ? j : i1;
    q2 = nq2; h2 = nh2; i2 = ni2;
  }
  sRI1[sl][lane] = i1;
  sRI2[sl][lane] = i2;
  __syncthreads();

  // ---- wave 0 epilogue: all decisions + outputs in f64; f32 stores ----
  if (sl == 0) {
    double akD[DD], dxD[DD];
    double r2 = 0.0;
    #pragma unroll
    for (int d = 0; d < DD; ++d) {
      double a = xformD((double)anchor_raw[k * DD + d], sMnD[d], sSclD[d]);
      akD[d] = a;
      double dx = sOmcD[d] * (x4d[d] - a);
      dxD[d] = dx;
      r2 = fma(dx, dx, r2);
    }
    double rD = sqrt(r2);
    double rr = fmax(rD, 1e-12);          // jnp.maximum(r, 1e-12)
    double ratio = rD / 1e9;              // all-invalid fallback: r/BIG

    #pragma unroll
    for (int ss = 0; ss < SLICES; ++ss) {
      #pragma unroll
      for (int t = 0; t < 2; ++t) {
        int j = t ? sRI2[ss][lane] : sRI1[ss][lane];
        if (j < 0 || j == k) continue;
        double q = 0.0, h = 0.0;
        #pragma unroll
        for (int d = 0; d < DD; ++d) {
          double aj = xformD((double)anchor_raw[j * DD + d], sMnD[d], sSclD[d]);
          double g = aj - akD[d];
          q = fma(dxD[d], g, q);
          h = fma(g, g, h);
        }
        double proj = q / rr;             // u·(a_j - a_k)
        if (proj > 1e-12) {
          double cand = rD * proj / (0.5 * h);
          ratio = fmax(ratio, cand);
        }
      }
    }
    #pragma unroll
    for (int d = 0; d < DD; ++d) {
      double u = dxD[d] / rr;
      if (u > 1e-12)        ratio = fmax(ratio, rD * u / (sMxD[d] - akD[d]));
      else if (u < -1e-12)  ratio = fmax(ratio, rD * u / (sMnD[d] - akD[d]));
    }

    double sS = 1.0 / (1.0 - ratio);
    float* xo = out + (size_t)row * DD;
    #pragma unroll
    for (int d = 0; d < DD; ++d) {
      double x7 = dxD[d] * sS;                      // (x_k + dx*s) - x_k
      double x8 = (x7 + sB2D[d]) * sE2D[d];         // actnorm2
      xo[d] = (float)x8;
    }
    double lp = (double)logp_in[row] + sBaseD + lsigD
              + 17.0 * log1p(-ratio)                // (D+1)*log1p(-ratio)
              - (double)mlogits[k];                 // LSE folded into sBaseD
    out[(size_t)Brows * DD + row] = (float)lp;
    out[coreEnd + (size_t)row * KK + k] = 1.0f;
  }
}

extern "C" void kernel_launch(void* const* d_in, const int* in_sizes, int n_in,
                              void* d_out, int out_size, void* d_ws, size_t ws_size,
                              hipStream_t stream) {
  (void)n_in; (void)out_size; (void)d_ws; (void)ws_size;
  const float* x_in   = (const float*)d_in[0];
  const float* logp   = (const float*)d_in[1];
  const float* an1w   = (const float*)d_in[2];
  const float* an1b   = (const float*)d_in[3];
  const float* an2w   = (const float*)d_in[4];
  const float* an2b   = (const float*)d_in[5];
  const float* shiftc = (const float*)d_in[6];
  const float* anchor = (const float*)d_in[7];
  const float* bmin   = (const float*)d_in[8];
  const float* bmax   = (const float*)d_in[9];
  const float* mlog   = (const float*)d_in[10];
  const int B = in_sizes[0] / DD;
  dim3 grid(B / RPB), block(NT);
  hipLaunchKernelGGL(vor_main, grid, block, 0, stream,
                     x_in, logp, an1w, an1b, an2w, an2b, shiftc, anchor,
                     bmin, bmax, mlog, (float*)d_out, B);
}